// Round 10
// baseline (152.530 us; speedup 1.0000x reference)
//
#include <hip/hip_runtime.h>
#include <hip/hip_bf16.h>

// 1-NN VQ via split-bf16 MFMA + exact fp32 refinement.
//   score[q][k] = csq[k] - 2*dot(q,c_k); out = argmin_k (lowest-k tie-break).
// Phase 0 (knn_prep): codebook -> bf16 hi/lo fragment-ready cbB (kb-major) + csq.
// Phase A (knn_mfma): persistent codebook, 3 waves/SIMD barrier-free (r19).
//   Evidence ladder: r16 1w/SIMD=51us, r17 2w no-barrier=39us, r18 2w
//   +per-batch barrier (halved LDS traffic!)=53us -> kernel is LATENCY/
//   ISSUE-bound, responds to TLP not LDS-bytes (MfmaUtil ~18% in all).
//   Lockstep waves stall together (A-wait, ds-wait, epilogue shfl chains).
//   r19: r17 structure (m=1, full 16 n-tiles/wave, no merge, no steady
//   barriers) at 768 thr / 12 waves / 3 per SIMD, launch_bounds(768,3)
//   (cap 512/3~170). Reg fit: csq FOLDED INTO ACC INIT (acc[t] = -csq/2,
//   final acc = -score/2, epilogue = pure max-top-2, no fmaf) -> live ~=
//   64 AGPR acc + 32 ah/al + 16 cs + ~40 temps ~= 155 <= 170.
//   Work: 32 q-chunks (16 q) per block over 12 waves x 3 rounds; round 2
//   waves 8-11 idle via wave-uniform guard (no barrier inside guard).
//   Grid 256 -> all CUs busy. B fill: 128 x 1KB gload_lds chunks strided
//   over 12 waves; ONE barrier ever (bt==0, all waves valid there).
//   dot ~= qh.ch+ql.ch+qh.cl (err ~1.9e-3); gap 2(bf-sf) < T=0.004 ->
//   worklist (ties -> refine exact lowest-k pass).
// Phase B (knn_refine): exact fp32 rescan (u64 keys, lowest-k tie-break).
// Tripwire: WRITE_SIZE > 2 MB => 170-cap spill => revert to 512thr+prefetch.

typedef __bf16 bf16x8 __attribute__((ext_vector_type(8)));
typedef float  floatx4 __attribute__((ext_vector_type(4)));

#define MFMA16 __builtin_amdgcn_mfma_f32_16x16x32_bf16

#define CNT_OFF 0
#define CSQ_OFF 1024
#define CBB_OFF 4096
#define WL_OFF  (4096 + 131072)
#define WL_CAP  32768
#define T_FLAG  0.004f

typedef __attribute__((address_space(1))) const unsigned int gu32;
typedef __attribute__((address_space(3))) unsigned int lu32;

__device__ __forceinline__ unsigned fmap(float f) {
    unsigned u = __float_as_uint(f);
    return (u & 0x80000000u) ? ~u : (u | 0x80000000u);
}

// ---------------- Phase 0: codebook split, kb-major fragment layout, csq ----------------
// cbB element index = ((kb*16 + t)*2 + part)*512 + ln*8 + j   (= id*8 below)
//   kb = k-chunk 0..3; t = ntile 0..15; part: 0=hi 1=lo;
//   lane ln: n = t*16 + (ln&15), k = kb*32 + (ln>>4)*8 + j.
__global__ void knn_prep(const float* __restrict__ cb, __bf16* __restrict__ cbB,
                         float* __restrict__ csq, int* __restrict__ cnt) {
    const int tid = threadIdx.x;
    const int id = blockIdx.x * 256 + tid;       // 0..8191
    if (id == 0) *cnt = 0;
    const int ln = id & 63;
    const int part = (id >> 6) & 1;
    const int step = id >> 7;                    // kb*16 + t
    const int t4 = step & 15;
    const int kb = step >> 4;
    const int n = t4 * 16 + (ln & 15);
    const int k0 = kb * 32 + (ln >> 4) * 8;
    const float* src = cb + (size_t)n * 128 + k0;
    union { __bf16 h[8]; uint4 u; } p;
#pragma unroll
    for (int j = 0; j < 8; ++j) {
        float f = src[j];
        __bf16 hh = (__bf16)f;
        p.h[j] = (part == 0) ? hh : (__bf16)(f - (float)hh);
    }
    *(uint4*)(cbB + (size_t)id * 8) = p.u;

    if (blockIdx.x == 0) {
        const float4* row = (const float4*)(cb + (size_t)tid * 128);
        float a0 = 0.f, a1 = 0.f, a2 = 0.f, a3 = 0.f;
#pragma unroll 8
        for (int j = 0; j < 32; ++j) {
            float4 v = row[j];
            a0 = fmaf(v.x, v.x, a0);
            a1 = fmaf(v.y, v.y, a1);
            a2 = fmaf(v.z, v.z, a2);
            a3 = fmaf(v.w, v.w, a3);
        }
        csq[tid] = (a0 + a1) + (a2 + a3);
    }
}

// ---------------- Phase A: persistent-codebook MFMA scores + top-2 + flag ----------------
__global__ __launch_bounds__(768, 3) void knn_mfma(const float* __restrict__ x,
                                                   const __bf16* __restrict__ cbB,
                                                   const float* __restrict__ csq_g,
                                                   int* __restrict__ out,
                                                   int* __restrict__ cnt,
                                                   int* __restrict__ wl) {
    __shared__ __bf16 sB[65536];                 // 128 KB: ENTIRE split codebook

    const int tid = threadIdx.x;
    const int wave = tid >> 6;                   // 0..11 (3 waves/SIMD)
    const int lane = tid & 63;
    const int rl = lane & 15;                    // n col within tile
    const int kg = lane >> 4;                    // k-group / q-row group 0..3

    // ---- one-time B fill: 128 x 1 KB chunks strided over 12 waves ----
#pragma unroll
    for (int i = 0; i < 11; ++i) {
        const int c = wave + 12 * i;
        if (c < 128) {
            const char* g = (const char*)cbB + c * 1024 + lane * 16;
            char* l = (char*)sB + c * 1024;
            __builtin_amdgcn_global_load_lds((gu32*)g, (lu32*)l, 16, 0, 0);
        }
    }

    float cs[16];
#pragma unroll
    for (int t = 0; t < 16; ++t) cs[t] = csq_g[t * 16 + rl];   // L1-hot, once

    // ---- 3 rounds x 12 waves over 32 q-chunks of 16 ----
#pragma unroll 1
    for (int bt = 0; bt < 3; ++bt) {
        const int c = bt * 12 + wave;            // chunk id 0..35
        const bool valid = (c < 32);
        const size_t q0 = (size_t)blockIdx.x * 512 + (size_t)c * 16;

        bf16x8 ah[4], al[4];
        floatx4 acc[16];

        if (valid) {
            // ---- A: load + split-convert this wave's m-tile into registers ----
            const float* xq = x + q0 * 128;
#pragma unroll
            for (int kb = 0; kb < 4; ++kb) {
                const float* s = xq + (size_t)rl * 128 + kb * 32 + kg * 8;
                float4 f0 = *(const float4*)(s);
                float4 f1 = *(const float4*)(s + 4);
                float f[8] = {f0.x, f0.y, f0.z, f0.w, f1.x, f1.y, f1.z, f1.w};
                union { __bf16 h[8]; bf16x8 v; } ph, pl;
#pragma unroll
                for (int j = 0; j < 8; ++j) {
                    __bf16 hh = (__bf16)f[j];
                    ph.h[j] = hh;
                    pl.h[j] = (__bf16)(f[j] - (float)hh);
                }
                ah[kb] = ph.v;
                al[kb] = pl.v;
            }
            // acc init = -csq/2: final acc = dot - csq/2 = -score/2 (maximize)
#pragma unroll
            for (int t = 0; t < 16; ++t) {
                const float iv = -0.5f * cs[t];
                acc[t] = (floatx4){iv, iv, iv, iv};
            }
        }

        if (bt == 0) __syncthreads();            // B fill landed; all waves valid here

        if (valid) {
            // ---- K-loop: pure LDS reads + MFMA, no barriers ----
            // element offset = kb*16384 + t*1024 + part*512 + lane*8
#pragma unroll
            for (int kb = 0; kb < 4; ++kb) {
                const __bf16* sbase = sB + kb * 16384 + lane * 8;
#pragma unroll
                for (int t = 0; t < 16; ++t) {
                    bf16x8 bh = *(const bf16x8*)(sbase + t * 1024);
                    bf16x8 bl = *(const bf16x8*)(sbase + t * 1024 + 512);
                    acc[t] = MFMA16(ah[kb], bh, acc[t], 0, 0, 0);
                    acc[t] = MFMA16(al[kb], bh, acc[t], 0, 0, 0);
                    acc[t] = MFMA16(ah[kb], bl, acc[t], 0, 0, 0);
                }
            }

            // ---- epilogue: max-domain per-wave top-2 (ties -> refine) ----
#pragma unroll
            for (int r = 0; r < 4; ++r) {
                float bf = -__builtin_inff(), sf = -__builtin_inff();
                int bi = 0;
#pragma unroll
                for (int t = 0; t < 16; ++t) {
                    const float sc = acc[t][r];
                    const bool gt = sc > bf;
                    sf = gt ? bf : fmaxf(sf, sc);
                    bf = gt ? sc : bf;
                    bi = gt ? (t * 16 + rl) : bi;
                }
#pragma unroll
                for (int d = 1; d < 16; d <<= 1) {
                    const float obf = __shfl_xor(bf, d);
                    const int   obi = __shfl_xor(bi, d);
                    const float osf = __shfl_xor(sf, d);
                    const bool gt = obf > bf;
                    const float loser = gt ? bf : obf;       // smaller best
                    sf = fmaxf(fmaxf(sf, osf), loser);
                    bf = gt ? obf : bf;
                    bi = gt ? obi : bi;
                }
                if (rl == 0) {
                    const size_t qg = q0 + kg * 4 + r;
                    out[qg] = bi;
                    // score gap = 2*(bf - sf)
                    if (2.0f * (bf - sf) < T_FLAG) {
                        int idx = atomicAdd(cnt, 1);
                        if (idx < WL_CAP) wl[idx] = (int)qg;
                    }
                }
            }
        }
    }
}

// ---------------- Phase B: exact fp32 rescan, block-per-query ----------------
__global__ __launch_bounds__(256) void knn_refine(const float* __restrict__ x,
                                                  const float* __restrict__ cb,
                                                  const float* __restrict__ csq_g,
                                                  const int* __restrict__ wl,
                                                  const int* __restrict__ cnt,
                                                  int* __restrict__ out) {
    __shared__ unsigned long long sP[4];
    const int tid = threadIdx.x;           // == code index k
    const int lane = tid & 63;
    const int wave = tid >> 6;

    int n = *cnt;
    if (n > WL_CAP) n = WL_CAP;
    const float mycsq = csq_g[tid];
    const float4* cr = (const float4*)(cb + (size_t)tid * 128);

    for (int i = blockIdx.x; i < n; i += gridDim.x) {
        const int q = wl[i];
        const float4* qr = (const float4*)(x + (size_t)q * 128);
        float a0 = 0.f, a1 = 0.f, a2 = 0.f, a3 = 0.f;
#pragma unroll 8
        for (int c4 = 0; c4 < 32; ++c4) {
            float4 qv = qr[c4];            // broadcast (same addr all lanes)
            float4 cv = cr[c4];
            a0 = fmaf(qv.x, cv.x, a0);
            a1 = fmaf(qv.y, cv.y, a1);
            a2 = fmaf(qv.z, cv.z, a2);
            a3 = fmaf(qv.w, cv.w, a3);
        }
        float dot = (a0 + a1) + (a2 + a3);
        float score = fmaf(-2.0f, dot, mycsq);
        unsigned long long key =
            ((unsigned long long)fmap(score) << 32) | (unsigned)tid;
#pragma unroll
        for (int d = 1; d < 64; d <<= 1) {
            unsigned long long o = __shfl_xor(key, d);
            key = o < key ? o : key;
        }
        if (lane == 0) sP[wave] = key;
        __syncthreads();
        if (tid == 0) {
            unsigned long long b = sP[0];
            unsigned long long o;
            o = sP[1]; b = o < b ? o : b;
            o = sP[2]; b = o < b ? o : b;
            o = sP[3]; b = o < b ? o : b;
            out[q] = (int)(unsigned)(b & 0xFFFFFFFFull);
        }
        __syncthreads();
    }
}

extern "C" void kernel_launch(void* const* d_in, const int* in_sizes, int n_in,
                              void* d_out, int out_size, void* d_ws, size_t ws_size,
                              hipStream_t stream) {
    const float* x = (const float*)d_in[0];
    const float* cb = (const float*)d_in[1];
    int* out = (int*)d_out;

    char* ws = (char*)d_ws;
    int* cnt = (int*)(ws + CNT_OFF);
    float* csq = (float*)(ws + CSQ_OFF);
    __bf16* cbB = (__bf16*)(ws + CBB_OFF);
    int* wl = (int*)(ws + WL_OFF);

    const int M = in_sizes[0] / 128;     // 131072

    knn_prep<<<32, 256, 0, stream>>>(cb, cbB, csq, cnt);
    knn_mfma<<<M / 512, 768, 0, stream>>>(x, cbB, csq, out, cnt, wl);
    knn_refine<<<240, 256, 0, stream>>>(x, cb, csq, wl, cnt, out);
}

// Round 11
// 126.488 us; speedup vs baseline: 1.2059x; 1.2059x over previous
//
#include <hip/hip_runtime.h>
#include <hip/hip_bf16.h>

// 1-NN VQ via split-bf16 MFMA + exact fp32 refinement.
//   score[q][k] = csq[k] - 2*dot(q,c_k); out = argmin_k (lowest-k tie-break).
// Phase 0 (knn_prep): codebook -> bf16 hi/lo fragment-ready cbB (kb-major) + csq.
// Phase A (knn_mfma): persistent codebook, 2 w/SIMD barrier-free + overlap (r20).
//   Ladder: r16 1w=51us | r17 2w no-barrier=39us (BEST) | r18 +barrier=53 |
//   r19 3w/EU=69 (ALLOCATOR CLIFF: cap 170 -> compiler demoted the whole
//   64-reg acc array to scratch; VGPR=84, WRITE 51MB. Lesson: never pair a
//   64-reg acc array with a 3w/EU cap). Kernel is latency/issue-bound;
//   TLP=2 is the max that compiles clean; barriers are poison.
//   r20 = r17 + intra-wave overlap (no occupancy/regalloc risk, ~140 VGPR
//   vs 256 cap):
//   (1) cross-batch A-prefetch (T14): next batch's 8 float4 loads issued
//       right after K-loop, converted next iteration -> HBM latency hides
//       under epilogue shfl chains;
//   (2) SIMD antiphase (correct: partners are {w,w+4}): be=(bt+2*(wave>>2))&3
//       -> partner mid-K-loop while this wave converts/reduces;
//   (3) s_setprio(1) around K-loop (T5 condition now holds: independent
//       waves at different phases, attn-like +4-7%);
//   (4) r19's csq-fold: acc init = -csq/2 -> acc = -score/2, max-domain
//       epilogue, no fmaf (verified on HW in r19).
//   Structure: whole split codebook (128 KB) in LDS once (16x gload_lds
//   w=16/wave, linear dest); ONE barrier ever (bt==0); 4 batches x 16 q per
//   wave; K-loop pure ds_read_b128+MFMA; dot ~= qh.ch+ql.ch+qh.cl (err
//   ~1.9e-3); top-2 gap 2(bf-sf) < T=0.004 -> worklist.
// Phase B (knn_refine): exact fp32 rescan (u64 keys, lowest-k tie-break).
// Tripwire: WRITE_SIZE > 2 MB => prefetch blew the reg budget => drop (1).

typedef __bf16 bf16x8 __attribute__((ext_vector_type(8)));
typedef float  floatx4 __attribute__((ext_vector_type(4)));

#define MFMA16 __builtin_amdgcn_mfma_f32_16x16x32_bf16

#define CNT_OFF 0
#define CSQ_OFF 1024
#define CBB_OFF 4096
#define WL_OFF  (4096 + 131072)
#define WL_CAP  32768
#define T_FLAG  0.004f

typedef __attribute__((address_space(1))) const unsigned int gu32;
typedef __attribute__((address_space(3))) unsigned int lu32;

__device__ __forceinline__ unsigned fmap(float f) {
    unsigned u = __float_as_uint(f);
    return (u & 0x80000000u) ? ~u : (u | 0x80000000u);
}

// ---------------- Phase 0: codebook split, kb-major fragment layout, csq ----------------
// cbB element index = ((kb*16 + t)*2 + part)*512 + ln*8 + j   (= id*8 below)
//   kb = k-chunk 0..3; t = ntile 0..15; part: 0=hi 1=lo;
//   lane ln: n = t*16 + (ln&15), k = kb*32 + (ln>>4)*8 + j.
__global__ void knn_prep(const float* __restrict__ cb, __bf16* __restrict__ cbB,
                         float* __restrict__ csq, int* __restrict__ cnt) {
    const int tid = threadIdx.x;
    const int id = blockIdx.x * 256 + tid;       // 0..8191
    if (id == 0) *cnt = 0;
    const int ln = id & 63;
    const int part = (id >> 6) & 1;
    const int step = id >> 7;                    // kb*16 + t
    const int t4 = step & 15;
    const int kb = step >> 4;
    const int n = t4 * 16 + (ln & 15);
    const int k0 = kb * 32 + (ln >> 4) * 8;
    const float* src = cb + (size_t)n * 128 + k0;
    union { __bf16 h[8]; uint4 u; } p;
#pragma unroll
    for (int j = 0; j < 8; ++j) {
        float f = src[j];
        __bf16 hh = (__bf16)f;
        p.h[j] = (part == 0) ? hh : (__bf16)(f - (float)hh);
    }
    *(uint4*)(cbB + (size_t)id * 8) = p.u;

    if (blockIdx.x == 0) {
        const float4* row = (const float4*)(cb + (size_t)tid * 128);
        float a0 = 0.f, a1 = 0.f, a2 = 0.f, a3 = 0.f;
#pragma unroll 8
        for (int j = 0; j < 32; ++j) {
            float4 v = row[j];
            a0 = fmaf(v.x, v.x, a0);
            a1 = fmaf(v.y, v.y, a1);
            a2 = fmaf(v.z, v.z, a2);
            a3 = fmaf(v.w, v.w, a3);
        }
        csq[tid] = (a0 + a1) + (a2 + a3);
    }
}

// ---------------- Phase A: persistent-codebook MFMA scores + top-2 + flag ----------------
__global__ __launch_bounds__(512, 2) void knn_mfma(const float* __restrict__ x,
                                                   const __bf16* __restrict__ cbB,
                                                   const float* __restrict__ csq_g,
                                                   int* __restrict__ out,
                                                   int* __restrict__ cnt,
                                                   int* __restrict__ wl) {
    __shared__ __bf16 sB[65536];                 // 128 KB: ENTIRE split codebook

    const int tid = threadIdx.x;
    const int wave = tid >> 6;                   // 0..7 (2 waves/SIMD: {w, w+4})
    const int lane = tid & 63;
    const int rl = lane & 15;                    // n col within tile
    const int kg = lane >> 4;                    // k-group / q-row group 0..3
    const int ph = (wave >> 2) & 1;              // SIMD antiphase bit

    const size_t qbase = (size_t)blockIdx.x * 512 + wave * 16;
    const float* xw = x + (qbase + rl) * 128 + kg * 8;   // per-lane A row base

    // ---- prefetch A for first batch (be = 2*ph), BEFORE the B fill ----
    float4 pf[8];
    {
        const float* xs = xw + (size_t)((2 * ph) & 3) * 128 * 128;
#pragma unroll
        for (int kb = 0; kb < 4; ++kb) {
            pf[2 * kb]     = *(const float4*)(xs + kb * 32);
            pf[2 * kb + 1] = *(const float4*)(xs + kb * 32 + 4);
        }
    }

    // ---- one-time B fill: wave w copies 16 KB (16 x 1 KB, linear) ----
    {
        const char* gsrc = (const char*)cbB + wave * 16384 + lane * 16;
        char* ldst = (char*)sB + wave * 16384;
#pragma unroll
        for (int i = 0; i < 16; ++i)
            __builtin_amdgcn_global_load_lds((gu32*)(gsrc + i * 1024),
                                             (lu32*)(ldst + i * 1024), 16, 0, 0);
    }

    float cs[16];
#pragma unroll
    for (int t = 0; t < 16; ++t) cs[t] = csq_g[t * 16 + rl];   // L1-hot, once

    // ---- 4 batches of 16 q per wave; SIMD partners in antiphase ----
#pragma unroll 1
    for (int bt = 0; bt < 4; ++bt) {
        const int be = (bt + 2 * ph) & 3;        // this wave's batch index
        const size_t q0 = qbase + (size_t)be * 128;

        // ---- convert prefetched A: split into bf16 hi/lo fragments ----
        bf16x8 ah[4], al[4];
#pragma unroll
        for (int kb = 0; kb < 4; ++kb) {
            const float4 f0 = pf[2 * kb];
            const float4 f1 = pf[2 * kb + 1];
            float f[8] = {f0.x, f0.y, f0.z, f0.w, f1.x, f1.y, f1.z, f1.w};
            union { __bf16 h[8]; bf16x8 v; } phv, plv;
#pragma unroll
            for (int j = 0; j < 8; ++j) {
                __bf16 hh = (__bf16)f[j];
                phv.h[j] = hh;
                plv.h[j] = (__bf16)(f[j] - (float)hh);
            }
            ah[kb] = phv.v;
            al[kb] = plv.v;
        }

        // acc init = -csq/2: final acc = dot - csq/2 = -score/2 (maximize)
        floatx4 acc[16];
#pragma unroll
        for (int t = 0; t < 16; ++t) {
            const float iv = -0.5f * cs[t];
            acc[t] = (floatx4){iv, iv, iv, iv};
        }

        if (bt == 0) __syncthreads();            // B fill landed (vmcnt drain), once

        // ---- K-loop: pure LDS reads + MFMA, no barriers ----
        // element offset = kb*16384 + t*1024 + part*512 + lane*8
        __builtin_amdgcn_s_setprio(1);
#pragma unroll
        for (int kb = 0; kb < 4; ++kb) {
            const __bf16* sbase = sB + kb * 16384 + lane * 8;
#pragma unroll
            for (int t = 0; t < 16; ++t) {
                bf16x8 bh = *(const bf16x8*)(sbase + t * 1024);
                bf16x8 bl = *(const bf16x8*)(sbase + t * 1024 + 512);
                acc[t] = MFMA16(ah[kb], bh, acc[t], 0, 0, 0);
                acc[t] = MFMA16(al[kb], bh, acc[t], 0, 0, 0);
                acc[t] = MFMA16(ah[kb], bl, acc[t], 0, 0, 0);
            }
        }
        __builtin_amdgcn_s_setprio(0);

        // ---- issue next batch's A prefetch (hides HBM under epilogue) ----
        if (bt < 3) {
            const int nbe = (bt + 1 + 2 * ph) & 3;
            const float* xs = xw + (size_t)nbe * 128 * 128;
#pragma unroll
            for (int kb = 0; kb < 4; ++kb) {
                pf[2 * kb]     = *(const float4*)(xs + kb * 32);
                pf[2 * kb + 1] = *(const float4*)(xs + kb * 32 + 4);
            }
        }

        // ---- epilogue: max-domain per-wave top-2 (ties -> refine) ----
#pragma unroll
        for (int r = 0; r < 4; ++r) {
            float bf = -__builtin_inff(), sf = -__builtin_inff();
            int bi = 0;
#pragma unroll
            for (int t = 0; t < 16; ++t) {
                const float sc = acc[t][r];
                const bool gt = sc > bf;
                sf = gt ? bf : fmaxf(sf, sc);
                bf = gt ? sc : bf;
                bi = gt ? (t * 16 + rl) : bi;
            }
#pragma unroll
            for (int d = 1; d < 16; d <<= 1) {
                const float obf = __shfl_xor(bf, d);
                const int   obi = __shfl_xor(bi, d);
                const float osf = __shfl_xor(sf, d);
                const bool gt = obf > bf;
                const float loser = gt ? bf : obf;           // smaller best
                sf = fmaxf(fmaxf(sf, osf), loser);
                bf = gt ? obf : bf;
                bi = gt ? obi : bi;
            }
            if (rl == 0) {
                const size_t qg = q0 + kg * 4 + r;
                out[qg] = bi;
                // score gap = 2*(bf - sf)
                if (2.0f * (bf - sf) < T_FLAG) {
                    int idx = atomicAdd(cnt, 1);
                    if (idx < WL_CAP) wl[idx] = (int)qg;
                }
            }
        }
    }
}

// ---------------- Phase B: exact fp32 rescan, block-per-query ----------------
__global__ __launch_bounds__(256) void knn_refine(const float* __restrict__ x,
                                                  const float* __restrict__ cb,
                                                  const float* __restrict__ csq_g,
                                                  const int* __restrict__ wl,
                                                  const int* __restrict__ cnt,
                                                  int* __restrict__ out) {
    __shared__ unsigned long long sP[4];
    const int tid = threadIdx.x;           // == code index k
    const int lane = tid & 63;
    const int wave = tid >> 6;

    int n = *cnt;
    if (n > WL_CAP) n = WL_CAP;
    const float mycsq = csq_g[tid];
    const float4* cr = (const float4*)(cb + (size_t)tid * 128);

    for (int i = blockIdx.x; i < n; i += gridDim.x) {
        const int q = wl[i];
        const float4* qr = (const float4*)(x + (size_t)q * 128);
        float a0 = 0.f, a1 = 0.f, a2 = 0.f, a3 = 0.f;
#pragma unroll 8
        for (int c4 = 0; c4 < 32; ++c4) {
            float4 qv = qr[c4];            // broadcast (same addr all lanes)
            float4 cv = cr[c4];
            a0 = fmaf(qv.x, cv.x, a0);
            a1 = fmaf(qv.y, cv.y, a1);
            a2 = fmaf(qv.z, cv.z, a2);
            a3 = fmaf(qv.w, cv.w, a3);
        }
        float dot = (a0 + a1) + (a2 + a3);
        float score = fmaf(-2.0f, dot, mycsq);
        unsigned long long key =
            ((unsigned long long)fmap(score) << 32) | (unsigned)tid;
#pragma unroll
        for (int d = 1; d < 64; d <<= 1) {
            unsigned long long o = __shfl_xor(key, d);
            key = o < key ? o : key;
        }
        if (lane == 0) sP[wave] = key;
        __syncthreads();
        if (tid == 0) {
            unsigned long long b = sP[0];
            unsigned long long o;
            o = sP[1]; b = o < b ? o : b;
            o = sP[2]; b = o < b ? o : b;
            o = sP[3]; b = o < b ? o : b;
            out[q] = (int)(unsigned)(b & 0xFFFFFFFFull);
        }
        __syncthreads();
    }
}

extern "C" void kernel_launch(void* const* d_in, const int* in_sizes, int n_in,
                              void* d_out, int out_size, void* d_ws, size_t ws_size,
                              hipStream_t stream) {
    const float* x = (const float*)d_in[0];
    const float* cb = (const float*)d_in[1];
    int* out = (int*)d_out;

    char* ws = (char*)d_ws;
    int* cnt = (int*)(ws + CNT_OFF);
    float* csq = (float*)(ws + CSQ_OFF);
    __bf16* cbB = (__bf16*)(ws + CBB_OFF);
    int* wl = (int*)(ws + WL_OFF);

    const int M = in_sizes[0] / 128;     // 131072

    knn_prep<<<32, 256, 0, stream>>>(cb, cbB, csq, cnt);
    knn_mfma<<<M / 512, 512, 0, stream>>>(x, cbB, csq, out, cnt, wl);
    knn_refine<<<240, 256, 0, stream>>>(x, cb, csq, wl, cnt, out);
}

// Round 12
// 120.180 us; speedup vs baseline: 1.2692x; 1.0525x over previous
//
#include <hip/hip_runtime.h>
#include <hip/hip_bf16.h>

// 1-NN VQ via split-bf16 MFMA + exact fp32 refinement.
//   score[q][k] = csq[k] - 2*dot(q,c_k); out = argmin_k (lowest-k tie-break).
// Phase 0 (knn_prep): codebook -> bf16 hi/lo fragment-ready cbB (kb-major) + csq.
// Phase A (knn_mfma): r21 = r17 chassis + A-prefetch ONLY (single-variable).
//   Ladder: r16 1w/SIMD=51.5 | r17 2w lockstep barrier-free=~39 (BEST, total
//   121.9) | r18 +per-batch barrier=53 | r19 3w/EU reg-cap=69 (allocator
//   demoted acc to scratch) | r20 bundle(prefetch+antiphase+setprio+csqfold)
//   =58-64, no spill -> likely culprit: antiphase x setprio starved the
//   partner wave's epilogue (lockstep-equal-prio never starves; guide's GEMM
//   setprio result is negative). Lesson: single-change only from here.
//   r21 change: T14 issue-early/convert-late A-prefetch. r17 exposes ~900cy
//   of x-load latency at each batch top (unroll-1 blocks compiler pipelining
//   across iterations); issuing the next batch's 8 float4 loads right after
//   the K-loop hides that latency under the ~1200cy epilogue. No reordering,
//   no setprio, no csq-fold; K-loop/epilogue byte-identical to r17.
//   Structure: whole split codebook (128 KB) in LDS once (16x gload_lds
//   w=16/wave, linear dest); ONE barrier ever (bt==0); 4 batches x 16 q per
//   wave (m=1, all 16 n-tiles); K-loop pure ds_read_b128+MFMA; dot ~=
//   qh.ch+ql.ch+qh.cl (err ~1.9e-3); float-domain top-2, gap < T=0.004 ->
//   worklist (ties -> refine exact lowest-k pass).
// Phase B (knn_refine): exact fp32 rescan (u64 keys, lowest-k tie-break).
// Tripwire: WRITE_SIZE > 2 MB => prefetch blew regalloc => r17 is final.

typedef __bf16 bf16x8 __attribute__((ext_vector_type(8)));
typedef float  floatx4 __attribute__((ext_vector_type(4)));

#define MFMA16 __builtin_amdgcn_mfma_f32_16x16x32_bf16

#define CNT_OFF 0
#define CSQ_OFF 1024
#define CBB_OFF 4096
#define WL_OFF  (4096 + 131072)
#define WL_CAP  32768
#define T_FLAG  0.004f

typedef __attribute__((address_space(1))) const unsigned int gu32;
typedef __attribute__((address_space(3))) unsigned int lu32;

__device__ __forceinline__ unsigned fmap(float f) {
    unsigned u = __float_as_uint(f);
    return (u & 0x80000000u) ? ~u : (u | 0x80000000u);
}

// ---------------- Phase 0: codebook split, kb-major fragment layout, csq ----------------
// cbB element index = ((kb*16 + t)*2 + part)*512 + ln*8 + j   (= id*8 below)
//   kb = k-chunk 0..3; t = ntile 0..15; part: 0=hi 1=lo;
//   lane ln: n = t*16 + (ln&15), k = kb*32 + (ln>>4)*8 + j.
__global__ void knn_prep(const float* __restrict__ cb, __bf16* __restrict__ cbB,
                         float* __restrict__ csq, int* __restrict__ cnt) {
    const int tid = threadIdx.x;
    const int id = blockIdx.x * 256 + tid;       // 0..8191
    if (id == 0) *cnt = 0;
    const int ln = id & 63;
    const int part = (id >> 6) & 1;
    const int step = id >> 7;                    // kb*16 + t
    const int t4 = step & 15;
    const int kb = step >> 4;
    const int n = t4 * 16 + (ln & 15);
    const int k0 = kb * 32 + (ln >> 4) * 8;
    const float* src = cb + (size_t)n * 128 + k0;
    union { __bf16 h[8]; uint4 u; } p;
#pragma unroll
    for (int j = 0; j < 8; ++j) {
        float f = src[j];
        __bf16 hh = (__bf16)f;
        p.h[j] = (part == 0) ? hh : (__bf16)(f - (float)hh);
    }
    *(uint4*)(cbB + (size_t)id * 8) = p.u;

    if (blockIdx.x == 0) {
        const float4* row = (const float4*)(cb + (size_t)tid * 128);
        float a0 = 0.f, a1 = 0.f, a2 = 0.f, a3 = 0.f;
#pragma unroll 8
        for (int j = 0; j < 32; ++j) {
            float4 v = row[j];
            a0 = fmaf(v.x, v.x, a0);
            a1 = fmaf(v.y, v.y, a1);
            a2 = fmaf(v.z, v.z, a2);
            a3 = fmaf(v.w, v.w, a3);
        }
        csq[tid] = (a0 + a1) + (a2 + a3);
    }
}

// ---------------- Phase A: persistent-codebook MFMA scores + top-2 + flag ----------------
__global__ __launch_bounds__(512, 2) void knn_mfma(const float* __restrict__ x,
                                                   const __bf16* __restrict__ cbB,
                                                   const float* __restrict__ csq_g,
                                                   int* __restrict__ out,
                                                   int* __restrict__ cnt,
                                                   int* __restrict__ wl) {
    __shared__ __bf16 sB[65536];                 // 128 KB: ENTIRE split codebook

    const int tid = threadIdx.x;
    const int wave = tid >> 6;                   // 0..7 (2 waves/SIMD, lockstep)
    const int lane = tid & 63;
    const int rl = lane & 15;                    // n col within tile
    const int kg = lane >> 4;                    // k-group / q-row group 0..3

    const size_t qbase = (size_t)blockIdx.x * 512 + wave * 16;
    const float* xw = x + (qbase + rl) * 128 + kg * 8;   // per-lane A row base

    // ---- prefetch A for batch 0 (issued before the B fill) ----
    float4 pf[8];
#pragma unroll
    for (int kb = 0; kb < 4; ++kb) {
        pf[2 * kb]     = *(const float4*)(xw + kb * 32);
        pf[2 * kb + 1] = *(const float4*)(xw + kb * 32 + 4);
    }

    // ---- one-time B fill: wave w copies 16 KB (16 x 1 KB, linear) ----
    {
        const char* gsrc = (const char*)cbB + wave * 16384 + lane * 16;
        char* ldst = (char*)sB + wave * 16384;
#pragma unroll
        for (int i = 0; i < 16; ++i)
            __builtin_amdgcn_global_load_lds((gu32*)(gsrc + i * 1024),
                                             (lu32*)(ldst + i * 1024), 16, 0, 0);
    }

    float cs[16];
#pragma unroll
    for (int t = 0; t < 16; ++t) cs[t] = csq_g[t * 16 + rl];   // L1-hot, once

    // ---- 4 batches of 16 q per wave (lockstep, no reordering) ----
#pragma unroll 1
    for (int bt = 0; bt < 4; ++bt) {
        const size_t q0 = qbase + (size_t)bt * 128;

        // ---- convert prefetched A: split into bf16 hi/lo fragments ----
        bf16x8 ah[4], al[4];
#pragma unroll
        for (int kb = 0; kb < 4; ++kb) {
            const float4 f0 = pf[2 * kb];
            const float4 f1 = pf[2 * kb + 1];
            float f[8] = {f0.x, f0.y, f0.z, f0.w, f1.x, f1.y, f1.z, f1.w};
            union { __bf16 h[8]; bf16x8 v; } phv, plv;
#pragma unroll
            for (int j = 0; j < 8; ++j) {
                __bf16 hh = (__bf16)f[j];
                phv.h[j] = hh;
                plv.h[j] = (__bf16)(f[j] - (float)hh);
            }
            ah[kb] = phv.v;
            al[kb] = plv.v;
        }

        floatx4 acc[16];
#pragma unroll
        for (int t = 0; t < 16; ++t) acc[t] = (floatx4){0.f, 0.f, 0.f, 0.f};

        if (bt == 0) __syncthreads();            // B fill landed (vmcnt drain), once

        // ---- K-loop: pure LDS reads + MFMA, no barriers, no setprio ----
        // element offset = kb*16384 + t*1024 + part*512 + lane*8
#pragma unroll
        for (int kb = 0; kb < 4; ++kb) {
            const __bf16* sbase = sB + kb * 16384 + lane * 8;
#pragma unroll
            for (int t = 0; t < 16; ++t) {
                bf16x8 bh = *(const bf16x8*)(sbase + t * 1024);
                bf16x8 bl = *(const bf16x8*)(sbase + t * 1024 + 512);
                acc[t] = MFMA16(ah[kb], bh, acc[t], 0, 0, 0);
                acc[t] = MFMA16(al[kb], bh, acc[t], 0, 0, 0);
                acc[t] = MFMA16(ah[kb], bl, acc[t], 0, 0, 0);
            }
        }

        // ---- issue next batch's A loads (latency hides under epilogue) ----
        if (bt < 3) {
            const float* xs = xw + (size_t)(bt + 1) * 128 * 128;
#pragma unroll
            for (int kb = 0; kb < 4; ++kb) {
                pf[2 * kb]     = *(const float4*)(xs + kb * 32);
                pf[2 * kb + 1] = *(const float4*)(xs + kb * 32 + 4);
            }
        }

        // ---- epilogue: float-domain per-wave top-2 (ties -> refine) ----
#pragma unroll
        for (int r = 0; r < 4; ++r) {
            float bf = __builtin_inff(), sf = __builtin_inff();
            int bi = 0;
#pragma unroll
            for (int t = 0; t < 16; ++t) {
                const float sc = fmaf(-2.0f, acc[t][r], cs[t]);
                const bool lt = sc < bf;
                sf = lt ? bf : fminf(sf, sc);
                bf = lt ? sc : bf;
                bi = lt ? (t * 16 + rl) : bi;
            }
#pragma unroll
            for (int d = 1; d < 16; d <<= 1) {
                const float obf = __shfl_xor(bf, d);
                const int   obi = __shfl_xor(bi, d);
                const float osf = __shfl_xor(sf, d);
                const bool lt = obf < bf;
                const float loser = lt ? bf : obf;           // larger best
                sf = fminf(fminf(sf, osf), loser);
                bf = lt ? obf : bf;
                bi = lt ? obi : bi;
            }
            if (rl == 0) {
                const size_t qg = q0 + kg * 4 + r;
                out[qg] = bi;
                if (sf - bf < T_FLAG) {          // gap small (or tie) -> exact pass
                    int idx = atomicAdd(cnt, 1);
                    if (idx < WL_CAP) wl[idx] = (int)qg;
                }
            }
        }
    }
}

// ---------------- Phase B: exact fp32 rescan, block-per-query ----------------
__global__ __launch_bounds__(256) void knn_refine(const float* __restrict__ x,
                                                  const float* __restrict__ cb,
                                                  const float* __restrict__ csq_g,
                                                  const int* __restrict__ wl,
                                                  const int* __restrict__ cnt,
                                                  int* __restrict__ out) {
    __shared__ unsigned long long sP[4];
    const int tid = threadIdx.x;           // == code index k
    const int lane = tid & 63;
    const int wave = tid >> 6;

    int n = *cnt;
    if (n > WL_CAP) n = WL_CAP;
    const float mycsq = csq_g[tid];
    const float4* cr = (const float4*)(cb + (size_t)tid * 128);

    for (int i = blockIdx.x; i < n; i += gridDim.x) {
        const int q = wl[i];
        const float4* qr = (const float4*)(x + (size_t)q * 128);
        float a0 = 0.f, a1 = 0.f, a2 = 0.f, a3 = 0.f;
#pragma unroll 8
        for (int c4 = 0; c4 < 32; ++c4) {
            float4 qv = qr[c4];            // broadcast (same addr all lanes)
            float4 cv = cr[c4];
            a0 = fmaf(qv.x, cv.x, a0);
            a1 = fmaf(qv.y, cv.y, a1);
            a2 = fmaf(qv.z, cv.z, a2);
            a3 = fmaf(qv.w, cv.w, a3);
        }
        float dot = (a0 + a1) + (a2 + a3);
        float score = fmaf(-2.0f, dot, mycsq);
        unsigned long long key =
            ((unsigned long long)fmap(score) << 32) | (unsigned)tid;
#pragma unroll
        for (int d = 1; d < 64; d <<= 1) {
            unsigned long long o = __shfl_xor(key, d);
            key = o < key ? o : key;
        }
        if (lane == 0) sP[wave] = key;
        __syncthreads();
        if (tid == 0) {
            unsigned long long b = sP[0];
            unsigned long long o;
            o = sP[1]; b = o < b ? o : b;
            o = sP[2]; b = o < b ? o : b;
            o = sP[3]; b = o < b ? o : b;
            out[q] = (int)(unsigned)(b & 0xFFFFFFFFull);
        }
        __syncthreads();
    }
}

extern "C" void kernel_launch(void* const* d_in, const int* in_sizes, int n_in,
                              void* d_out, int out_size, void* d_ws, size_t ws_size,
                              hipStream_t stream) {
    const float* x = (const float*)d_in[0];
    const float* cb = (const float*)d_in[1];
    int* out = (int*)d_out;

    char* ws = (char*)d_ws;
    int* cnt = (int*)(ws + CNT_OFF);
    float* csq = (float*)(ws + CSQ_OFF);
    __bf16* cbB = (__bf16*)(ws + CBB_OFF);
    int* wl = (int*)(ws + WL_OFF);

    const int M = in_sizes[0] / 128;     // 131072

    knn_prep<<<32, 256, 0, stream>>>(cb, cbB, csq, cnt);
    knn_mfma<<<M / 512, 512, 0, stream>>>(x, cbB, csq, out, cnt, wl);
    knn_refine<<<240, 256, 0, stream>>>(x, cb, csq, wl, cnt, out);
}